// Round 8
// baseline (242.799 us; speedup 1.0000x reference)
//
#include <hip/hip_runtime.h>

// LearnablePatchify: Conv2d(3->3, k=s=28) -> channel-mean -> broadcast per patch.
// Algebra: channel-mean commutes with the contraction:
//   m[b,hp,wp] = sum_{c,i,j} x[b,c,hp*28+i,wp*28+j] * Wm[c,i,j] + bm,
//   Wm = mean_o W[o], bm = mean(b); out[b, hp*16+wp, :, :] = m (broadcast).
// x[64,3,448,448] f32 (154 MB), out[64,256,28,28] f32 (51 MB); floor ~33 us.
//
// R3 design: R0/R1/R2 (coalesced / scattered / LDS-staged) all tied (~237-250)
// => reads were never the limiter. The only thing measured at stream rate on
// this box is the harness fill kernel: no barriers, no LDS, ~8 VGPR, one pure
// stream. Mimic it: 3 kernels through ws.
//   K0: Wm=mean_o W (588 f4) + bm -> ws            (tiny, one block)
//   K1: pure READ stream: wave-per-patch dot-reduce, no LDS/barriers,
//       magic-number f->(c,i,j4) decomposition, 1 float out per wave -> ws.m
//   K2: pure WRITE stream: wave-per-patch broadcast of m, plain f4 stores.
// ws layout (floats): [0..2351]=Wm, [2352]=bm, [2560..18943]=m (16B-aligned).

typedef float f32x4 __attribute__((ext_vector_type(4)));

#define WS_M_OFF 2560  // float offset of m[] in ws

__global__ __launch_bounds__(256) void k0_prep(
    const float* __restrict__ W, const float* __restrict__ bias,
    float* __restrict__ ws) {
  const int t = threadIdx.x;
  const float4* W4 = reinterpret_cast<const float4*>(W);
  float4* o = reinterpret_cast<float4*>(ws);
  for (int f = t; f < 588; f += 256) {
    const float4 a = W4[f], g = W4[f + 588], h = W4[f + 1176];
    o[f] = make_float4((a.x + g.x + h.x) * (1.f / 3.f),
                       (a.y + g.y + h.y) * (1.f / 3.f),
                       (a.z + g.z + h.z) * (1.f / 3.f),
                       (a.w + g.w + h.w) * (1.f / 3.f));
  }
  if (t == 0) ws[2352] = (bias[0] + bias[1] + bias[2]) * (1.f / 3.f);
}

// K1: one wave per patch; 588 f4 fragments, lane handles f = it*64+lane.
__global__ __launch_bounds__(256) void k1_reduce(
    const float* __restrict__ x, const float* __restrict__ ws_w,
    float* __restrict__ ws_m) {
  const int t    = threadIdx.x;
  const int lane = t & 63;
  const int P    = blockIdx.x * 4 + (t >> 6);  // 0..16383
  const int b    = P >> 8;
  const int rem  = P & 255;
  const int hp   = rem >> 4;
  const int wp   = rem & 15;

  const char* xbase = reinterpret_cast<const char*>(
      x + (size_t)b * 602112 + (size_t)hp * 12544 + wp * 28);
  const float4* wm4 = reinterpret_cast<const float4*>(ws_w);

  float s = 0.f;
  #pragma unroll
  for (int it = 0; it < 9; ++it) {
    const int f  = it * 64 + lane;                 // < 576
    const int c  = (f * 1339) >> 18;               // f/196 (valid f<588)
    const int r2 = f - c * 196;
    const int i  = (r2 * 9363) >> 16;              // r2/7
    const int j4 = r2 - i * 7;
    const float4 v = *reinterpret_cast<const float4*>(
        xbase + c * 802816 + i * 1792 + j4 * 16);  // HBM stream
    const float4 w = wm4[f];                       // L2-hot, lane-contiguous
    s += v.x * w.x + v.y * w.y + v.z * w.z + v.w * w.w;
  }
  {  // tail f = 576 + lane, valid lanes 0..11
    const int f = 576 + lane;
    if (f < 588) {
      const int c  = (f * 1339) >> 18;
      const int r2 = f - c * 196;
      const int i  = (r2 * 9363) >> 16;
      const int j4 = r2 - i * 7;
      const float4 v = *reinterpret_cast<const float4*>(
          xbase + c * 802816 + i * 1792 + j4 * 16);
      const float4 w = wm4[f];
      s += v.x * w.x + v.y * w.y + v.z * w.z + v.w * w.w;
    }
  }
  #pragma unroll
  for (int m = 32; m >= 1; m >>= 1) s += __shfl_xor(s, m, 64);
  if (lane == 0) ws_m[P] = s + ws_w[2352];  // + bm
}

// K2: one wave per patch; broadcast m[P] over 196 contiguous f4 (plain stores).
__global__ __launch_bounds__(256) void k2_write(
    const float* __restrict__ ws_m, float* __restrict__ out) {
  const int t    = threadIdx.x;
  const int lane = t & 63;
  const int P    = blockIdx.x * 4 + (t >> 6);
  const float s  = ws_m[P];                        // same-addr broadcast load
  f32x4* o4 = reinterpret_cast<f32x4*>(out + (size_t)P * 784);
  const f32x4 val = {s, s, s, s};
  #pragma unroll
  for (int it = 0; it < 4; ++it) {
    const int idx = it * 64 + lane;
    if (idx < 196) o4[idx] = val;
  }
}

extern "C" void kernel_launch(void* const* d_in, const int* in_sizes, int n_in,
                              void* d_out, int out_size, void* d_ws, size_t ws_size,
                              hipStream_t stream) {
  const float* x    = (const float*)d_in[0];
  const float* W    = (const float*)d_in[1];
  const float* bias = (const float*)d_in[2];
  float* out = (float*)d_out;
  float* ws  = (float*)d_ws;
  k0_prep <<<dim3(1),    dim3(256), 0, stream>>>(W, bias, ws);
  k1_reduce<<<dim3(4096), dim3(256), 0, stream>>>(x, ws, ws + WS_M_OFF);
  k2_write <<<dim3(4096), dim3(256), 0, stream>>>(ws + WS_M_OFF, out);
}

// Round 12
// 235.824 us; speedup vs baseline: 1.0296x; 1.0296x over previous
//
#include <hip/hip_runtime.h>

// LearnablePatchify: Conv2d(3->3, k=s=28) -> channel-mean -> broadcast per patch.
// Algebra: channel-mean commutes with the contraction:
//   m[b,hp,wp] = sum_{c,i,j} x[b,c,hp*28+i,wp*28+j] * Wm[c,i,j] + bm,
//   Wm = mean_o W[o], bm = mean(b); out[b, hp*16+wp, :, :] = m (broadcast).
// x[64,3,448,448] f32 (154 MB), out[64,256,28,28] f32 (51 MB).
//
// Session evidence (R1-R8): four structurally different designs tie 236-250 us;
// the timed iteration is dominated by ~150 us of harness resets (616 MB
// ws-poison + 51 MB out-poison + 286 MB input-restore) + graph node bubbles.
// Best measured = single-kernel wave-per-patch (236.2). This round: that
// champion, consolidated — ONE launch node, LDS only for the 9.4 KB Wm table
// (one barrier), magic-number index math, NT stores for the write stream.

typedef float f32x4 __attribute__((ext_vector_type(4)));

__global__ __launch_bounds__(256) void patchify_kernel(
    const float* __restrict__ x, const float* __restrict__ W,
    const float* __restrict__ bias, float* __restrict__ out) {
  __shared__ float4 sW4[588];  // mean-over-o weights, f4-fragment order

  const int t    = threadIdx.x;
  const int lane = t & 63;

  // Prep: Wm = mean over the 3 output channels (W = 28 KB, L2-hot).
  if (t < 256) {
    for (int f = t; f < 588; f += 256) {
      const float4 a = reinterpret_cast<const float4*>(W)[f];
      const float4 g = reinterpret_cast<const float4*>(W)[f + 588];
      const float4 h = reinterpret_cast<const float4*>(W)[f + 1176];
      sW4[f] = make_float4((a.x + g.x + h.x) * (1.f / 3.f),
                           (a.y + g.y + h.y) * (1.f / 3.f),
                           (a.z + g.z + h.z) * (1.f / 3.f),
                           (a.w + g.w + h.w) * (1.f / 3.f));
    }
  }
  __syncthreads();  // only barrier

  const int P   = blockIdx.x * 4 + (t >> 6);  // patch id 0..16383
  const int b   = P >> 8;
  const int rem = P & 255;
  const int hp  = rem >> 4;
  const int wp  = rem & 15;

  const char* xbase = reinterpret_cast<const char*>(
      x + (size_t)b * 602112 + (size_t)hp * 12544 + wp * 28);

  float s = 0.f;
  #pragma unroll
  for (int it = 0; it < 9; ++it) {
    const int f  = it * 64 + lane;                 // < 576
    const int c  = (f * 1339) >> 18;               // f/196  (valid f<588)
    const int r2 = f - c * 196;
    const int i  = (r2 * 9363) >> 16;              // r2/7
    const int j4 = r2 - i * 7;
    const float4 v = *reinterpret_cast<const float4*>(
        xbase + c * 802816 + i * 1792 + j4 * 16);  // HBM read stream
    const float4 w = sW4[f];
    s += v.x * w.x + v.y * w.y + v.z * w.z + v.w * w.w;
  }
  {  // tail f = 576 + lane, valid lanes 0..11
    const int f = 576 + lane;
    if (f < 588) {
      const int c  = (f * 1339) >> 18;
      const int r2 = f - c * 196;
      const int i  = (r2 * 9363) >> 16;
      const int j4 = r2 - i * 7;
      const float4 v = *reinterpret_cast<const float4*>(
          xbase + c * 802816 + i * 1792 + j4 * 16);
      const float4 w = sW4[f];
      s += v.x * w.x + v.y * w.y + v.z * w.z + v.w * w.w;
    }
  }

  // 64-lane butterfly sum; bias loads are uniform + L1-hot.
  #pragma unroll
  for (int m = 32; m >= 1; m >>= 1) s += __shfl_xor(s, m, 64);
  s += (bias[0] + bias[1] + bias[2]) * (1.f / 3.f);

  // Patch write: 196 contiguous f4; NT stores keep L2/L3 for the x stream.
  f32x4* o4 = reinterpret_cast<f32x4*>(out + (size_t)P * 784);
  const f32x4 val = {s, s, s, s};
  #pragma unroll
  for (int it = 0; it < 4; ++it) {
    const int idx = it * 64 + lane;
    if (idx < 196) __builtin_nontemporal_store(val, o4 + idx);
  }
}

extern "C" void kernel_launch(void* const* d_in, const int* in_sizes, int n_in,
                              void* d_out, int out_size, void* d_ws, size_t ws_size,
                              hipStream_t stream) {
  const float* x    = (const float*)d_in[0];
  const float* W    = (const float*)d_in[1];
  const float* bias = (const float*)d_in[2];
  float* out = (float*)d_out;
  patchify_kernel<<<dim3(4096), dim3(256), 0, stream>>>(x, W, bias, out);
}